// Round 11
// baseline (702.918 us; speedup 1.0000x reference)
//
#include <hip/hip_runtime.h>

#define BB 512
#define TT 200
#define VV 2048
#define EE 20
#define HH 100
#define G4 400   // 4*H
#define II 64
#define AA 32
#define NT 25    // 16-wide tiles over gate dim 400 (rows reordered r' = 4j+g)
#define NCHUNK 64

typedef _Float16 half8 __attribute__((ext_vector_type(8)));
typedef float    f32x4 __attribute__((ext_vector_type(4)));

// ---------------- workspace layout (4-byte units) ----------------
#define WS_BF_OFF    1024                        // k1 W_emb B-frags: 65536 half
#define WS_WIHF_OFF  (WS_BF_OFF + 32768)         // W_ih' B-frags: 12800 half
#define WS_WHHF_OFF  (WS_WIHF_OFF + 6400)        // W_hh' A-frags: 51200 half
#define WS_BIASC_OFF (WS_WHHF_OFF + 25600)       // 400 f  (b_ih+b_hh, r' order)
#define WS_EMB_OFF   (WS_BIASC_OFF + 400)        // emb, COMPACTED rows: 102400x20 f
#define WS_XG_OFF    (WS_EMB_OFF + 2048000)      // xg: 102720x400 f (padded)

// ---------------- Kernel 0: prefix-sum + all weight fragment packs (FROZEN) ----------------
__global__ __launch_bounds__(512) void k0_prep(
    const int* __restrict__ lengths, const float* __restrict__ W_emb,
    const float* __restrict__ W_ih, const float* __restrict__ W_hh,
    const float* __restrict__ b_ih, const float* __restrict__ b_hh,
    int* __restrict__ off, _Float16* __restrict__ Bfrag,
    _Float16* __restrict__ Wihf, _Float16* __restrict__ Whhf,
    float* __restrict__ biasc)
{
    if (blockIdx.x == 0) {
        __shared__ int s[BB];
        int tid = threadIdx.x;
        s[tid] = lengths[tid];
        __syncthreads();
        for (int d = 1; d < BB; d <<= 1) {
            int v = (tid >= d) ? s[tid - d] : 0;
            __syncthreads();
            if (tid >= d) s[tid] += v;
            __syncthreads();
        }
        off[tid + 1] = s[tid];
        if (tid == 0) off[0] = 0;
        return;
    }
    int F = (blockIdx.x - 1) * 512 + threadIdx.x;
    if (F < 65536) {                       // k1 W_emb B-frags
        int e = F & 7, l = (F >> 3) & 63, nn = (F >> 9) & 1, c = F >> 10;
        int k = c * 32 + (l >> 4) * 8 + e;
        int col = nn * 16 + (l & 15);
        float v = (col < EE) ? W_emb[(size_t)col * VV + k] : 0.f;
        Bfrag[F] = (_Float16)v;
        return;
    }
    F -= 65536;
    if (F < 12800) {                       // W_ih' B-frags: [nt][lane][8]
        int e = F & 7, l = (F >> 3) & 63, nt = F >> 9;
        int rp = nt * 16 + (l & 15);       // r' = 4j+g
        int j = rp >> 2, g = rp & 3;
        int k = 8 * (l >> 4) + e;          // 0..31
        float v = (k < EE) ? W_ih[(size_t)(g * HH + j) * EE + k] : 0.f;
        Wihf[F] = (_Float16)v;
        return;
    }
    F -= 12800;
    if (F < 51200) {                       // W_hh' A-frags: [m][c][lane][8]
        int e = F & 7, l = (F >> 3) & 63, c = (F >> 9) & 3, m = F >> 11;
        int rp = m * 16 + (l & 15);
        int j = rp >> 2, g = rp & 3;
        int k = 32 * c + 8 * (l >> 4) + e; // 0..127
        float v = (k < HH) ? W_hh[(size_t)(g * HH + j) * HH + k] : 0.f;
        Whhf[F] = (_Float16)v;
        return;
    }
    F -= 51200;
    if (F < 400) {                         // biasc in r' order
        int j = F >> 2, g = F & 3;
        biasc[F] = b_ih[g * HH + j] + b_hh[g * HH + j];
    }
}

// ---------------- Kernel 1: embedding GEMM via MFMA fp16 -> COMPACTED emb (FROZEN) ----------------
__global__ __launch_bounds__(256) void k1_embed(
    const float* __restrict__ batch, const int* __restrict__ off,
    const _Float16* __restrict__ Bfrag, const float* __restrict__ b_emb,
    float* __restrict__ emb)
{
    const int Nv = off[BB];
    if (blockIdx.x * 64 >= Nv) return;

    const int lane  = threadIdx.x & 63;
    const int wid   = threadIdx.x >> 6;
    const int rbase = blockIdx.x * 64 + wid * 16;

    int lrow = rbase + (lane & 15);
    int lr = (lrow < Nv) ? lrow : (Nv - 1);
    int lo = 0, hi = BB;
    while (lo + 1 < hi) {
        int mid = (lo + hi) >> 1;
        if (off[mid] <= lr) lo = mid; else hi = mid;
    }
    const int lroff = lo * TT + (lr - off[lo]);   // (b*TT + t): batch-source row

    const float* __restrict__ aptr = batch + (size_t)lroff * VV + ((lane >> 4) * 8);
    const half8* __restrict__ bptr = reinterpret_cast<const half8*>(Bfrag) + lane;

    f32x4 acc0 = {0.f, 0.f, 0.f, 0.f};
    f32x4 acc1 = {0.f, 0.f, 0.f, 0.f};

#pragma unroll 4
    for (int c = 0; c < NCHUNK; ++c) {
        float4 a0 = *reinterpret_cast<const float4*>(aptr + c * 32);
        float4 a1 = *reinterpret_cast<const float4*>(aptr + c * 32 + 4);
        half8 b0 = bptr[(c * 2 + 0) * 64];
        half8 b1 = bptr[(c * 2 + 1) * 64];
        half8 av;
        av[0] = (_Float16)a0.x; av[1] = (_Float16)a0.y;
        av[2] = (_Float16)a0.z; av[3] = (_Float16)a0.w;
        av[4] = (_Float16)a1.x; av[5] = (_Float16)a1.y;
        av[6] = (_Float16)a1.z; av[7] = (_Float16)a1.w;
        acc0 = __builtin_amdgcn_mfma_f32_16x16x32_f16(av, b0, acc0, 0, 0, 0);
        acc1 = __builtin_amdgcn_mfma_f32_16x16x32_f16(av, b1, acc1, 0, 0, 0);
    }

    const int col0 = lane & 15;
    const float bias0 = b_emb[col0];
    const float bias1 = (col0 < 4) ? b_emb[16 + col0] : 0.f;
#pragma unroll
    for (int r = 0; r < 4; ++r) {
        int srow = rbase + (lane >> 4) * 4 + r;   // compacted destination row
        if (srow < Nv) {
            emb[(size_t)srow * EE + col0] = acc0[r] + bias0;
            if (col0 < 4)
                emb[(size_t)srow * EE + 16 + col0] = acc1[r] + bias1;
        }
    }
}

// ---------------- Kernel 1b: xg = emb @ W_ih'^T + biasc (FROZEN) ----------------
__global__ __launch_bounds__(256, 2) void k1_xg(
    const float* __restrict__ emb, const int* __restrict__ off,
    const _Float16* __restrict__ Wihf, const float* __restrict__ biasc,
    float* __restrict__ xg)
{
    __shared__ __align__(16) uint4 wl[NT * 64];   // 25600 B
    __shared__ float bl[G4];

    const int tid = threadIdx.x;
    const int Nv = off[BB];
    for (int i = tid; i < NT * 64; i += 256) wl[i] = reinterpret_cast<const uint4*>(Wihf)[i];
    for (int i = tid; i < G4; i += 256) bl[i] = biasc[i];
    __syncthreads();

    const int lane = tid & 63, wid = tid >> 6;
    const int T = blockIdx.x * 4 + wid;
    if (T * 16 >= Nv) return;

    const int lr = min(T * 16 + (lane & 15), Nv - 1);
    const int kb = (lane >> 4) * 8;
    const float* ap = emb + (size_t)lr * EE;
    float4 p0 = make_float4(0.f, 0.f, 0.f, 0.f), p1 = p0;
    if (kb < EE)     p0 = *reinterpret_cast<const float4*>(ap + kb);
    if (kb + 4 < EE) p1 = *reinterpret_cast<const float4*>(ap + kb + 4);
    half8 av;
    av[0] = (_Float16)p0.x; av[1] = (_Float16)p0.y;
    av[2] = (_Float16)p0.z; av[3] = (_Float16)p0.w;
    av[4] = (_Float16)p1.x; av[5] = (_Float16)p1.y;
    av[6] = (_Float16)p1.z; av[7] = (_Float16)p1.w;

    const int rbase = T * 16 + 4 * (lane >> 4);
    const int cl = lane & 15;
#pragma unroll
    for (int nt = 0; nt < NT; ++nt) {
        half8 bf = *reinterpret_cast<const half8*>(&wl[nt * 64 + lane]);
        f32x4 a = {0.f, 0.f, 0.f, 0.f};
        a = __builtin_amdgcn_mfma_f32_16x16x32_f16(av, bf, a, 0, 0, 0);
        float bias = bl[nt * 16 + cl];
#pragma unroll
        for (int r = 0; r < 4; ++r) {
            if (rbase + r < Nv)
                xg[(size_t)(rbase + r) * G4 + nt * 16 + cl] = a[r] + bias;
        }
    }
}

// ---------------- Kernel 2: MFMA LSTM scan — DIAGNOSTIC: scan runs 2x ----------------
__device__ __forceinline__ float fast_sig(float x) { return 1.f / (1.f + __expf(-x)); }
__device__ __forceinline__ float fast_tanh(float x) { return 2.f * fast_sig(2.f * x) - 1.f; }

#define STEP(T_, CUR_, XC_, XN_)  do {                                                        \
    uint4 rb0_ = *reinterpret_cast<const uint4*>(&bfrag[CUR_][0][lane][0]);                   \
    uint4 rb1_ = *reinterpret_cast<const uint4*>(&bfrag[CUR_][1][lane][0]);                   \
    uint4 rb2_ = *reinterpret_cast<const uint4*>(&bfrag[CUR_][2][lane][0]);                   \
    uint4 rb3_ = *reinterpret_cast<const uint4*>(&bfrag[CUR_][3][lane][0]);                   \
    _Pragma("unroll")                                                                         \
    for (int it = 0; it < 4; ++it) if (it < ntile)                                            \
        XN_[it] = *reinterpret_cast<const float4*>(xg + rowbase + (size_t)((T_) + 1) * G4 + xgoff[it]); \
    _Pragma("unroll")                                                                         \
    for (int it = 0; it < 4; ++it) if (it < ntile) {                                          \
        f32x4 acc = __builtin_bit_cast(f32x4, XC_[it]);                                       \
        acc = __builtin_amdgcn_mfma_f32_16x16x32_f16(af[it][0], __builtin_bit_cast(half8, rb0_), acc, 0, 0, 0); \
        acc = __builtin_amdgcn_mfma_f32_16x16x32_f16(af[it][1], __builtin_bit_cast(half8, rb1_), acc, 0, 0, 0); \
        acc = __builtin_amdgcn_mfma_f32_16x16x32_f16(af[it][2], __builtin_bit_cast(half8, rb2_), acc, 0, 0, 0); \
        acc = __builtin_amdgcn_mfma_f32_16x16x32_f16(af[it][3], __builtin_bit_cast(half8, rb3_), acc, 0, 0, 0); \
        float gi = fast_sig(acc[0]);                                                          \
        float gf = fast_sig(acc[1]);                                                          \
        float gg = fast_tanh(acc[2]);                                                         \
        float go = fast_sig(acc[3]);                                                          \
        cst[it] = gf * cst[it] + gi * gg;                                                     \
        float hv = go * fast_tanh(cst[it]);                                                   \
        int j_ = jidx[it];                                                                    \
        if ((T_) == len_n - 1) hfin[n][j_] = hv;                                              \
        int kk_ = j_ & 31;                                                                    \
        _Float16* hp_ = (_Float16*)&bfrag[(CUR_) ^ 1][j_ >> 5][((kk_ >> 3) << 4) | n][(kk_ & 7) >> 1]; \
        hp_[kk_ & 1] = (_Float16)hv;                                                          \
    }                                                                                         \
    __syncthreads();                                                                          \
} while (0)

__global__ __launch_bounds__(512, 2) void k2_lstm(
    const float* __restrict__ xg, const int* __restrict__ lengths,
    const int* __restrict__ off, const _Float16* __restrict__ Whhf,
    const float* __restrict__ W1, const float* __restrict__ b1,
    const float* __restrict__ W2, const float* __restrict__ b2,
    const float* __restrict__ h0, const float* __restrict__ c0,
    float* __restrict__ out)
{
    __shared__ __align__(16) unsigned int bfrag[2][4][64][4];  // 8 KB fp16 B-frags
    __shared__ float hfin[16][HH];
    __shared__ float inter[16][II];
    __shared__ int len_s[16], off_s[16];

    const int tid  = threadIdx.x;
    const int lane = tid & 63;
    const int w    = tid >> 6;
    const int b0   = blockIdx.x * 16;
    const int n    = lane & 15, rg = lane >> 4;

    if (tid < 16) {
        len_s[tid] = lengths[b0 + tid];
        off_s[tid] = off[b0 + tid];
    }
    for (int i = tid; i < 2 * 4 * 64 * 4; i += 512) (&bfrag[0][0][0][0])[i] = 0u;
    __syncthreads();

    int tmax = 0;
#pragma unroll
    for (int k = 0; k < 16; ++k) tmax = max(tmax, len_s[k]);

    const int ntile = (w == 7) ? 4 : 3;
    const int m0    = (w < 7) ? 3 * w : 21;
    const int len_n = len_s[n];
    const size_t rowbase = (size_t)off_s[n] * G4;

    half8 af[4][4];
    float cst[4];
    int   jidx[4], xgoff[4];
    float4 xgA[4], xgB[4];
    // invariant setup (weights, indices) — once
#pragma unroll
    for (int it = 0; it < 4; ++it) if (it < ntile) {
        const int m = m0 + it;
#pragma unroll
        for (int c = 0; c < 4; ++c)
            af[it][c] = reinterpret_cast<const half8*>(Whhf)[((m * 4 + c) * 64) + lane];
        jidx[it]  = 4 * m + rg;
        xgoff[it] = 16 * m + 4 * rg;
    }

    // DIAGNOSTIC: run the full scan twice (bit-identical output; makes this
    // dispatch ~570us so it surfaces in the rocprof top-5 with counters).
    for (int rep = 0; rep < 2; ++rep) {
#pragma unroll
        for (int it = 0; it < 4; ++it) if (it < ntile) {
            const int j = jidx[it];
            cst[it] = c0[(size_t)(b0 + n) * HH + j];
            float hv = h0[(size_t)(b0 + n) * HH + j];
            int kk = j & 31;
            _Float16* hp = (_Float16*)&bfrag[0][j >> 5][((kk >> 3) << 4) | n][(kk & 7) >> 1];
            hp[kk & 1] = (_Float16)hv;
            xgA[it] = *reinterpret_cast<const float4*>(xg + rowbase + xgoff[it]);
        }
        __syncthreads();

        for (int t = 0; t < tmax; t += 2) {
            STEP(t, 0, xgA, xgB);
            if (t + 1 < tmax) STEP(t + 1, 1, xgB, xgA);
        }
    }

    // fused MLP over the 16 batches
    for (int o = tid; o < 16 * II; o += 512) {
        int nn = o >> 6, i = o & 63;
        float a = b1[i];
        const float* w1r = W1 + i * HH;
        const float* hr  = &hfin[nn][0];
#pragma unroll
        for (int k = 0; k < HH; k += 4) {
            a += w1r[k] * hr[k] + w1r[k + 1] * hr[k + 1]
               + w1r[k + 2] * hr[k + 2] + w1r[k + 3] * hr[k + 3];
        }
        inter[nn][i] = fmaxf(a, 0.f);
    }
    __syncthreads();
    for (int o = tid; o < 16 * AA; o += 512) {
        int nn = o >> 5, ai = o & 31;
        float a = b2[ai];
        const float* w2r = W2 + ai * II;
#pragma unroll
        for (int k = 0; k < II; ++k) a += w2r[k] * inter[nn][k];
        out[(size_t)(b0 + nn) * AA + ai] = a;
    }
}

extern "C" void kernel_launch(void* const* d_in, const int* in_sizes, int n_in,
                              void* d_out, int out_size, void* d_ws, size_t ws_size,
                              hipStream_t stream) {
    const float* batch  = (const float*)d_in[0];
    const int*   lengths= (const int*)  d_in[1];
    const float* W_emb  = (const float*)d_in[2];
    const float* b_emb  = (const float*)d_in[3];
    const float* W_ih   = (const float*)d_in[4];
    const float* W_hh   = (const float*)d_in[5];
    const float* b_ih   = (const float*)d_in[6];
    const float* b_hh   = (const float*)d_in[7];
    const float* W1     = (const float*)d_in[8];
    const float* b1     = (const float*)d_in[9];
    const float* W2     = (const float*)d_in[10];
    const float* b2     = (const float*)d_in[11];
    const float* h0     = (const float*)d_in[12];
    const float* c0     = (const float*)d_in[13];
    float* out = (float*)d_out;

    int*       off   = (int*)d_ws;
    float*     wsf   = (float*)d_ws;
    _Float16*  Bfrag = (_Float16*)(wsf + WS_BF_OFF);
    _Float16*  Wihf  = (_Float16*)(wsf + WS_WIHF_OFF);
    _Float16*  Whhf  = (_Float16*)(wsf + WS_WHHF_OFF);
    float*     biasc = wsf + WS_BIASC_OFF;
    float*     emb   = wsf + WS_EMB_OFF;
    float*     xg    = wsf + WS_XG_OFF;

    k0_prep<<<255, 512, 0, stream>>>(lengths, W_emb, W_ih, W_hh, b_ih, b_hh,
                                     off, Bfrag, Wihf, Whhf, biasc);
    k1_embed<<<(BB * TT + 63) / 64, 256, 0, stream>>>(batch, off, Bfrag, b_emb, emb);
    k1_xg<<<(BB * TT / 16 + 3) / 4, 256, 0, stream>>>(emb, off, Wihf, biasc, xg);
    k2_lstm<<<BB / 16, 512, 0, stream>>>(xg, lengths, off, Whhf,
                                         W1, b1, W2, b2, h0, c0, out);
}

// Round 12
// 493.468 us; speedup vs baseline: 1.4244x; 1.4244x over previous
//
#include <hip/hip_runtime.h>

#define BB 512
#define TT 200
#define VV 2048
#define EE 20
#define HH 100
#define G4 400   // 4*H
#define II 64
#define AA 32
#define NT 25    // 16-wide tiles over gate dim 400 (rows reordered r' = 4j+g)
#define NCHUNK 64

typedef _Float16 half8 __attribute__((ext_vector_type(8)));
typedef float    f32x4 __attribute__((ext_vector_type(4)));

// ---------------- workspace layout (4-byte units) ----------------
#define WS_BF_OFF    1024                        // k1 W_emb B-frags: 65536 half
#define WS_WIHF_OFF  (WS_BF_OFF + 32768)         // W_ih' B-frags: 12800 half
#define WS_WHHF_OFF  (WS_WIHF_OFF + 6400)        // W_hh' A-frags: 51200 half
#define WS_BIASC_OFF (WS_WHHF_OFF + 25600)       // 400 f  (b_ih+b_hh, r' order)
#define WS_EMB_OFF   (WS_BIASC_OFF + 400)        // emb, COMPACTED rows: 102400x20 f
#define WS_XG_OFF    (WS_EMB_OFF + 2048000)      // xg: 102720x400 f (padded)

// ---------------- Kernel 0: prefix-sum + all weight fragment packs (FROZEN) ----------------
__global__ __launch_bounds__(512) void k0_prep(
    const int* __restrict__ lengths, const float* __restrict__ W_emb,
    const float* __restrict__ W_ih, const float* __restrict__ W_hh,
    const float* __restrict__ b_ih, const float* __restrict__ b_hh,
    int* __restrict__ off, _Float16* __restrict__ Bfrag,
    _Float16* __restrict__ Wihf, _Float16* __restrict__ Whhf,
    float* __restrict__ biasc)
{
    if (blockIdx.x == 0) {
        __shared__ int s[BB];
        int tid = threadIdx.x;
        s[tid] = lengths[tid];
        __syncthreads();
        for (int d = 1; d < BB; d <<= 1) {
            int v = (tid >= d) ? s[tid - d] : 0;
            __syncthreads();
            if (tid >= d) s[tid] += v;
            __syncthreads();
        }
        off[tid + 1] = s[tid];
        if (tid == 0) off[0] = 0;
        return;
    }
    int F = (blockIdx.x - 1) * 512 + threadIdx.x;
    if (F < 65536) {                       // k1 W_emb B-frags
        int e = F & 7, l = (F >> 3) & 63, nn = (F >> 9) & 1, c = F >> 10;
        int k = c * 32 + (l >> 4) * 8 + e;
        int col = nn * 16 + (l & 15);
        float v = (col < EE) ? W_emb[(size_t)col * VV + k] : 0.f;
        Bfrag[F] = (_Float16)v;
        return;
    }
    F -= 65536;
    if (F < 12800) {                       // W_ih' B-frags: [nt][lane][8]
        int e = F & 7, l = (F >> 3) & 63, nt = F >> 9;
        int rp = nt * 16 + (l & 15);       // r' = 4j+g
        int j = rp >> 2, g = rp & 3;
        int k = 8 * (l >> 4) + e;          // 0..31
        float v = (k < EE) ? W_ih[(size_t)(g * HH + j) * EE + k] : 0.f;
        Wihf[F] = (_Float16)v;
        return;
    }
    F -= 12800;
    if (F < 51200) {                       // W_hh' A-frags: [m][c][lane][8]
        int e = F & 7, l = (F >> 3) & 63, c = (F >> 9) & 3, m = F >> 11;
        int rp = m * 16 + (l & 15);
        int j = rp >> 2, g = rp & 3;
        int k = 32 * c + 8 * (l >> 4) + e; // 0..127
        float v = (k < HH) ? W_hh[(size_t)(g * HH + j) * HH + k] : 0.f;
        Whhf[F] = (_Float16)v;
        return;
    }
    F -= 51200;
    if (F < 400) {                         // biasc in r' order
        int j = F >> 2, g = F & 3;
        biasc[F] = b_ih[g * HH + j] + b_hh[g * HH + j];
    }
}

// ---------------- Kernel 1: embedding GEMM via MFMA fp16 -> COMPACTED emb (FROZEN) ----------------
__global__ __launch_bounds__(256) void k1_embed(
    const float* __restrict__ batch, const int* __restrict__ off,
    const _Float16* __restrict__ Bfrag, const float* __restrict__ b_emb,
    float* __restrict__ emb)
{
    const int Nv = off[BB];
    if (blockIdx.x * 64 >= Nv) return;

    const int lane  = threadIdx.x & 63;
    const int wid   = threadIdx.x >> 6;
    const int rbase = blockIdx.x * 64 + wid * 16;

    int lrow = rbase + (lane & 15);
    int lr = (lrow < Nv) ? lrow : (Nv - 1);
    int lo = 0, hi = BB;
    while (lo + 1 < hi) {
        int mid = (lo + hi) >> 1;
        if (off[mid] <= lr) lo = mid; else hi = mid;
    }
    const int lroff = lo * TT + (lr - off[lo]);   // (b*TT + t): batch-source row

    const float* __restrict__ aptr = batch + (size_t)lroff * VV + ((lane >> 4) * 8);
    const half8* __restrict__ bptr = reinterpret_cast<const half8*>(Bfrag) + lane;

    f32x4 acc0 = {0.f, 0.f, 0.f, 0.f};
    f32x4 acc1 = {0.f, 0.f, 0.f, 0.f};

#pragma unroll 4
    for (int c = 0; c < NCHUNK; ++c) {
        float4 a0 = *reinterpret_cast<const float4*>(aptr + c * 32);
        float4 a1 = *reinterpret_cast<const float4*>(aptr + c * 32 + 4);
        half8 b0 = bptr[(c * 2 + 0) * 64];
        half8 b1 = bptr[(c * 2 + 1) * 64];
        half8 av;
        av[0] = (_Float16)a0.x; av[1] = (_Float16)a0.y;
        av[2] = (_Float16)a0.z; av[3] = (_Float16)a0.w;
        av[4] = (_Float16)a1.x; av[5] = (_Float16)a1.y;
        av[6] = (_Float16)a1.z; av[7] = (_Float16)a1.w;
        acc0 = __builtin_amdgcn_mfma_f32_16x16x32_f16(av, b0, acc0, 0, 0, 0);
        acc1 = __builtin_amdgcn_mfma_f32_16x16x32_f16(av, b1, acc1, 0, 0, 0);
    }

    const int col0 = lane & 15;
    const float bias0 = b_emb[col0];
    const float bias1 = (col0 < 4) ? b_emb[16 + col0] : 0.f;
#pragma unroll
    for (int r = 0; r < 4; ++r) {
        int srow = rbase + (lane >> 4) * 4 + r;   // compacted destination row
        if (srow < Nv) {
            emb[(size_t)srow * EE + col0] = acc0[r] + bias0;
            if (col0 < 4)
                emb[(size_t)srow * EE + 16 + col0] = acc1[r] + bias1;
        }
    }
}

// ---------------- Kernel 1b: xg = emb @ W_ih'^T + biasc (FROZEN) ----------------
__global__ __launch_bounds__(256, 2) void k1_xg(
    const float* __restrict__ emb, const int* __restrict__ off,
    const _Float16* __restrict__ Wihf, const float* __restrict__ biasc,
    float* __restrict__ xg)
{
    __shared__ __align__(16) uint4 wl[NT * 64];   // 25600 B
    __shared__ float bl[G4];

    const int tid = threadIdx.x;
    const int Nv = off[BB];
    for (int i = tid; i < NT * 64; i += 256) wl[i] = reinterpret_cast<const uint4*>(Wihf)[i];
    for (int i = tid; i < G4; i += 256) bl[i] = biasc[i];
    __syncthreads();

    const int lane = tid & 63, wid = tid >> 6;
    const int T = blockIdx.x * 4 + wid;
    if (T * 16 >= Nv) return;

    const int lr = min(T * 16 + (lane & 15), Nv - 1);
    const int kb = (lane >> 4) * 8;
    const float* ap = emb + (size_t)lr * EE;
    float4 p0 = make_float4(0.f, 0.f, 0.f, 0.f), p1 = p0;
    if (kb < EE)     p0 = *reinterpret_cast<const float4*>(ap + kb);
    if (kb + 4 < EE) p1 = *reinterpret_cast<const float4*>(ap + kb + 4);
    half8 av;
    av[0] = (_Float16)p0.x; av[1] = (_Float16)p0.y;
    av[2] = (_Float16)p0.z; av[3] = (_Float16)p0.w;
    av[4] = (_Float16)p1.x; av[5] = (_Float16)p1.y;
    av[6] = (_Float16)p1.z; av[7] = (_Float16)p1.w;

    const int rbase = T * 16 + 4 * (lane >> 4);
    const int cl = lane & 15;
#pragma unroll
    for (int nt = 0; nt < NT; ++nt) {
        half8 bf = *reinterpret_cast<const half8*>(&wl[nt * 64 + lane]);
        f32x4 a = {0.f, 0.f, 0.f, 0.f};
        a = __builtin_amdgcn_mfma_f32_16x16x32_f16(av, bf, a, 0, 0, 0);
        float bias = bl[nt * 16 + cl];
#pragma unroll
        for (int r = 0; r < 4; ++r) {
            if (rbase + r < Nv)
                xg[(size_t)(rbase + r) * G4 + nt * 16 + cl] = a[r] + bias;
        }
    }
}

// ---------------- Kernel 2: MFMA LSTM scan — non-draining barrier, split MFMA chain ----
__device__ __forceinline__ float fast_sig(float x) { return 1.f / (1.f + __expf(-x)); }
__device__ __forceinline__ float fast_tanh(float x) { return 2.f * fast_sig(2.f * x) - 1.f; }

// barrier that orders LDS (lgkmcnt) but leaves VMEM loads in flight
#define LDS_BARRIER() asm volatile("s_waitcnt lgkmcnt(0)\n\ts_barrier" ::: "memory")

#define STEP(T_, CUR_, XC_, XN_)  do {                                                        \
    uint4 rb0_ = *reinterpret_cast<const uint4*>(&bfrag[CUR_][0][lane][0]);                   \
    uint4 rb1_ = *reinterpret_cast<const uint4*>(&bfrag[CUR_][1][lane][0]);                   \
    uint4 rb2_ = *reinterpret_cast<const uint4*>(&bfrag[CUR_][2][lane][0]);                   \
    uint4 rb3_ = *reinterpret_cast<const uint4*>(&bfrag[CUR_][3][lane][0]);                   \
    _Pragma("unroll")                                                                         \
    for (int it = 0; it < 4; ++it) if (it < ntile)                                            \
        XN_[it] = *reinterpret_cast<const float4*>(xgp[it] + (size_t)((T_) + 1) * G4);        \
    _Pragma("unroll")                                                                         \
    for (int it = 0; it < 4; ++it) if (it < ntile) {                                          \
        f32x4 accA = __builtin_bit_cast(f32x4, XC_[it]);                                      \
        f32x4 accB = {0.f, 0.f, 0.f, 0.f};                                                    \
        accA = __builtin_amdgcn_mfma_f32_16x16x32_f16(af[it][0], __builtin_bit_cast(half8, rb0_), accA, 0, 0, 0); \
        accB = __builtin_amdgcn_mfma_f32_16x16x32_f16(af[it][2], __builtin_bit_cast(half8, rb2_), accB, 0, 0, 0); \
        accA = __builtin_amdgcn_mfma_f32_16x16x32_f16(af[it][1], __builtin_bit_cast(half8, rb1_), accA, 0, 0, 0); \
        accB = __builtin_amdgcn_mfma_f32_16x16x32_f16(af[it][3], __builtin_bit_cast(half8, rb3_), accB, 0, 0, 0); \
        float s0 = accA[0] + accB[0];                                                         \
        float s1 = accA[1] + accB[1];                                                         \
        float s2 = accA[2] + accB[2];                                                         \
        float s3 = accA[3] + accB[3];                                                         \
        float gi = fast_sig(s0);                                                              \
        float gf = fast_sig(s1);                                                              \
        float gg = fast_tanh(s2);                                                             \
        float go = fast_sig(s3);                                                              \
        cst[it] = gf * cst[it] + gi * gg;                                                     \
        float hv = go * fast_tanh(cst[it]);                                                   \
        int j_ = jidx[it];                                                                    \
        if ((T_) == len_n - 1) hfin[n][j_] = hv;                                              \
        int kk_ = j_ & 31;                                                                    \
        _Float16* hp_ = (_Float16*)&bfrag[(CUR_) ^ 1][j_ >> 5][((kk_ >> 3) << 4) | n][(kk_ & 7) >> 1]; \
        hp_[kk_ & 1] = (_Float16)hv;                                                          \
    }                                                                                         \
    LDS_BARRIER();                                                                            \
} while (0)

__global__ __launch_bounds__(512, 2) void k2_lstm(
    const float* __restrict__ xg, const int* __restrict__ lengths,
    const int* __restrict__ off, const _Float16* __restrict__ Whhf,
    const float* __restrict__ W1, const float* __restrict__ b1,
    const float* __restrict__ W2, const float* __restrict__ b2,
    const float* __restrict__ h0, const float* __restrict__ c0,
    float* __restrict__ out)
{
    __shared__ __align__(16) unsigned int bfrag[2][4][64][4];  // 8 KB fp16 B-frags
    __shared__ float hfin[16][HH];
    __shared__ float inter[16][II];
    __shared__ int len_s[16], off_s[16];

    const int tid  = threadIdx.x;
    const int lane = tid & 63;
    const int w    = tid >> 6;
    const int b0   = blockIdx.x * 16;
    const int n    = lane & 15, rg = lane >> 4;

    if (tid < 16) {
        len_s[tid] = lengths[b0 + tid];
        off_s[tid] = off[b0 + tid];
    }
    for (int i = tid; i < 2 * 4 * 64 * 4; i += 512) (&bfrag[0][0][0][0])[i] = 0u;
    __syncthreads();

    int tmax = 0;
#pragma unroll
    for (int k = 0; k < 16; ++k) tmax = max(tmax, len_s[k]);

    const int ntile = (w == 7) ? 4 : 3;
    const int m0    = (w < 7) ? 3 * w : 21;
    const int len_n = len_s[n];
    const size_t rowbase = (size_t)off_s[n] * G4;

    half8 af[4][4];
    float cst[4];
    int   jidx[4];
    const float* xgp[4];
    float4 xgA[4], xgB[4];
#pragma unroll
    for (int it = 0; it < 4; ++it) if (it < ntile) {
        const int m = m0 + it;
#pragma unroll
        for (int c = 0; c < 4; ++c)
            af[it][c] = reinterpret_cast<const half8*>(Whhf)[((m * 4 + c) * 64) + lane];
        const int j = 4 * m + rg;
        jidx[it] = j;
        xgp[it]  = xg + rowbase + 16 * m + 4 * rg;
        cst[it] = c0[(size_t)(b0 + n) * HH + j];
        float hv = h0[(size_t)(b0 + n) * HH + j];
        int kk = j & 31;
        _Float16* hp = (_Float16*)&bfrag[0][j >> 5][((kk >> 3) << 4) | n][(kk & 7) >> 1];
        hp[kk & 1] = (_Float16)hv;
        xgA[it] = *reinterpret_cast<const float4*>(xgp[it]);
    }
    __syncthreads();

    for (int t = 0; t < tmax; t += 2) {
        STEP(t, 0, xgA, xgB);
        if (t + 1 < tmax) STEP(t + 1, 1, xgB, xgA);
    }
    __syncthreads();

    // fused MLP over the 16 batches
    for (int o = tid; o < 16 * II; o += 512) {
        int nn = o >> 6, i = o & 63;
        float a = b1[i];
        const float* w1r = W1 + i * HH;
        const float* hr  = &hfin[nn][0];
#pragma unroll
        for (int k = 0; k < HH; k += 4) {
            a += w1r[k] * hr[k] + w1r[k + 1] * hr[k + 1]
               + w1r[k + 2] * hr[k + 2] + w1r[k + 3] * hr[k + 3];
        }
        inter[nn][i] = fmaxf(a, 0.f);
    }
    __syncthreads();
    for (int o = tid; o < 16 * AA; o += 512) {
        int nn = o >> 5, ai = o & 31;
        float a = b2[ai];
        const float* w2r = W2 + ai * II;
#pragma unroll
        for (int k = 0; k < II; ++k) a += w2r[k] * inter[nn][k];
        out[(size_t)(b0 + nn) * AA + ai] = a;
    }
}

extern "C" void kernel_launch(void* const* d_in, const int* in_sizes, int n_in,
                              void* d_out, int out_size, void* d_ws, size_t ws_size,
                              hipStream_t stream) {
    const float* batch  = (const float*)d_in[0];
    const int*   lengths= (const int*)  d_in[1];
    const float* W_emb  = (const float*)d_in[2];
    const float* b_emb  = (const float*)d_in[3];
    const float* W_ih   = (const float*)d_in[4];
    const float* W_hh   = (const float*)d_in[5];
    const float* b_ih   = (const float*)d_in[6];
    const float* b_hh   = (const float*)d_in[7];
    const float* W1     = (const float*)d_in[8];
    const float* b1     = (const float*)d_in[9];
    const float* W2     = (const float*)d_in[10];
    const float* b2     = (const float*)d_in[11];
    const float* h0     = (const float*)d_in[12];
    const float* c0     = (const float*)d_in[13];
    float* out = (float*)d_out;

    int*       off   = (int*)d_ws;
    float*     wsf   = (float*)d_ws;
    _Float16*  Bfrag = (_Float16*)(wsf + WS_BF_OFF);
    _Float16*  Wihf  = (_Float16*)(wsf + WS_WIHF_OFF);
    _Float16*  Whhf  = (_Float16*)(wsf + WS_WHHF_OFF);
    float*     biasc = wsf + WS_BIASC_OFF;
    float*     emb   = wsf + WS_EMB_OFF;
    float*     xg    = wsf + WS_XG_OFF;

    k0_prep<<<255, 512, 0, stream>>>(lengths, W_emb, W_ih, W_hh, b_ih, b_hh,
                                     off, Bfrag, Wihf, Whhf, biasc);
    k1_embed<<<(BB * TT + 63) / 64, 256, 0, stream>>>(batch, off, Bfrag, b_emb, emb);
    k1_xg<<<(BB * TT / 16 + 3) / 4, 256, 0, stream>>>(emb, off, Wihf, biasc, xg);
    k2_lstm<<<BB / 16, 512, 0, stream>>>(xg, lengths, off, Whhf,
                                         W1, b1, W2, b2, h0, c0, out);
}

// Round 13
// 443.452 us; speedup vs baseline: 1.5851x; 1.1128x over previous
//
#include <hip/hip_runtime.h>

#define BB 512
#define TT 200
#define VV 2048
#define EE 20
#define HH 100
#define G4 400   // 4*H
#define II 64
#define AA 32
#define NT 25    // 16-wide tiles over gate dim 400 (rows reordered r' = 4j+g)
#define NCHUNK 64

typedef _Float16 half8 __attribute__((ext_vector_type(8)));
typedef float    f32x4 __attribute__((ext_vector_type(4)));

// ---------------- workspace layout (4-byte units) ----------------
#define WS_BF_OFF    1024                        // k1 W_emb B-frags: 65536 half
#define WS_WIHF_OFF  (WS_BF_OFF + 32768)         // W_ih' B-frags: 12800 half
#define WS_WHHF_OFF  (WS_WIHF_OFF + 6400)        // W_hh' A-frags: 51200 half
#define WS_BIASC_OFF (WS_WHHF_OFF + 25600)       // 400 f  (b_ih+b_hh, r' order)
#define WS_EMB_OFF   (WS_BIASC_OFF + 400)        // emb, COMPACTED rows: 102400x20 f
#define WS_XG_OFF    (WS_EMB_OFF + 2048000)      // xg: 102720x400 f (padded)

// ---------------- Kernel 0: prefix-sum + all weight fragment packs (FROZEN) ----------------
__global__ __launch_bounds__(512) void k0_prep(
    const int* __restrict__ lengths, const float* __restrict__ W_emb,
    const float* __restrict__ W_ih, const float* __restrict__ W_hh,
    const float* __restrict__ b_ih, const float* __restrict__ b_hh,
    int* __restrict__ off, _Float16* __restrict__ Bfrag,
    _Float16* __restrict__ Wihf, _Float16* __restrict__ Whhf,
    float* __restrict__ biasc)
{
    if (blockIdx.x == 0) {
        __shared__ int s[BB];
        int tid = threadIdx.x;
        s[tid] = lengths[tid];
        __syncthreads();
        for (int d = 1; d < BB; d <<= 1) {
            int v = (tid >= d) ? s[tid - d] : 0;
            __syncthreads();
            if (tid >= d) s[tid] += v;
            __syncthreads();
        }
        off[tid + 1] = s[tid];
        if (tid == 0) off[0] = 0;
        return;
    }
    int F = (blockIdx.x - 1) * 512 + threadIdx.x;
    if (F < 65536) {                       // k1 W_emb B-frags
        int e = F & 7, l = (F >> 3) & 63, nn = (F >> 9) & 1, c = F >> 10;
        int k = c * 32 + (l >> 4) * 8 + e;
        int col = nn * 16 + (l & 15);
        float v = (col < EE) ? W_emb[(size_t)col * VV + k] : 0.f;
        Bfrag[F] = (_Float16)v;
        return;
    }
    F -= 65536;
    if (F < 12800) {                       // W_ih' B-frags: [nt][lane][8]
        int e = F & 7, l = (F >> 3) & 63, nt = F >> 9;
        int rp = nt * 16 + (l & 15);       // r' = 4j+g
        int j = rp >> 2, g = rp & 3;
        int k = 8 * (l >> 4) + e;          // 0..31
        float v = (k < EE) ? W_ih[(size_t)(g * HH + j) * EE + k] : 0.f;
        Wihf[F] = (_Float16)v;
        return;
    }
    F -= 12800;
    if (F < 51200) {                       // W_hh' A-frags: [m][c][lane][8]
        int e = F & 7, l = (F >> 3) & 63, c = (F >> 9) & 3, m = F >> 11;
        int rp = m * 16 + (l & 15);
        int j = rp >> 2, g = rp & 3;
        int k = 32 * c + 8 * (l >> 4) + e; // 0..127
        float v = (k < HH) ? W_hh[(size_t)(g * HH + j) * HH + k] : 0.f;
        Whhf[F] = (_Float16)v;
        return;
    }
    F -= 51200;
    if (F < 400) {                         // biasc in r' order
        int j = F >> 2, g = F & 3;
        biasc[F] = b_ih[g * HH + j] + b_hh[g * HH + j];
    }
}

// ---------------- Kernel 1: embedding GEMM via MFMA fp16 -> COMPACTED emb (FROZEN) ----------------
__global__ __launch_bounds__(256) void k1_embed(
    const float* __restrict__ batch, const int* __restrict__ off,
    const _Float16* __restrict__ Bfrag, const float* __restrict__ b_emb,
    float* __restrict__ emb)
{
    const int Nv = off[BB];
    if (blockIdx.x * 64 >= Nv) return;

    const int lane  = threadIdx.x & 63;
    const int wid   = threadIdx.x >> 6;
    const int rbase = blockIdx.x * 64 + wid * 16;

    int lrow = rbase + (lane & 15);
    int lr = (lrow < Nv) ? lrow : (Nv - 1);
    int lo = 0, hi = BB;
    while (lo + 1 < hi) {
        int mid = (lo + hi) >> 1;
        if (off[mid] <= lr) lo = mid; else hi = mid;
    }
    const int lroff = lo * TT + (lr - off[lo]);   // (b*TT + t): batch-source row

    const float* __restrict__ aptr = batch + (size_t)lroff * VV + ((lane >> 4) * 8);
    const half8* __restrict__ bptr = reinterpret_cast<const half8*>(Bfrag) + lane;

    f32x4 acc0 = {0.f, 0.f, 0.f, 0.f};
    f32x4 acc1 = {0.f, 0.f, 0.f, 0.f};

#pragma unroll 4
    for (int c = 0; c < NCHUNK; ++c) {
        float4 a0 = *reinterpret_cast<const float4*>(aptr + c * 32);
        float4 a1 = *reinterpret_cast<const float4*>(aptr + c * 32 + 4);
        half8 b0 = bptr[(c * 2 + 0) * 64];
        half8 b1 = bptr[(c * 2 + 1) * 64];
        half8 av;
        av[0] = (_Float16)a0.x; av[1] = (_Float16)a0.y;
        av[2] = (_Float16)a0.z; av[3] = (_Float16)a0.w;
        av[4] = (_Float16)a1.x; av[5] = (_Float16)a1.y;
        av[6] = (_Float16)a1.z; av[7] = (_Float16)a1.w;
        acc0 = __builtin_amdgcn_mfma_f32_16x16x32_f16(av, b0, acc0, 0, 0, 0);
        acc1 = __builtin_amdgcn_mfma_f32_16x16x32_f16(av, b1, acc1, 0, 0, 0);
    }

    const int col0 = lane & 15;
    const float bias0 = b_emb[col0];
    const float bias1 = (col0 < 4) ? b_emb[16 + col0] : 0.f;
#pragma unroll
    for (int r = 0; r < 4; ++r) {
        int srow = rbase + (lane >> 4) * 4 + r;   // compacted destination row
        if (srow < Nv) {
            emb[(size_t)srow * EE + col0] = acc0[r] + bias0;
            if (col0 < 4)
                emb[(size_t)srow * EE + 16 + col0] = acc1[r] + bias1;
        }
    }
}

// ---------------- Kernel 1b: xg = emb @ W_ih'^T + biasc (FROZEN) ----------------
__global__ __launch_bounds__(256, 2) void k1_xg(
    const float* __restrict__ emb, const int* __restrict__ off,
    const _Float16* __restrict__ Wihf, const float* __restrict__ biasc,
    float* __restrict__ xg)
{
    __shared__ __align__(16) uint4 wl[NT * 64];   // 25600 B
    __shared__ float bl[G4];

    const int tid = threadIdx.x;
    const int Nv = off[BB];
    for (int i = tid; i < NT * 64; i += 256) wl[i] = reinterpret_cast<const uint4*>(Wihf)[i];
    for (int i = tid; i < G4; i += 256) bl[i] = biasc[i];
    __syncthreads();

    const int lane = tid & 63, wid = tid >> 6;
    const int T = blockIdx.x * 4 + wid;
    if (T * 16 >= Nv) return;

    const int lr = min(T * 16 + (lane & 15), Nv - 1);
    const int kb = (lane >> 4) * 8;
    const float* ap = emb + (size_t)lr * EE;
    float4 p0 = make_float4(0.f, 0.f, 0.f, 0.f), p1 = p0;
    if (kb < EE)     p0 = *reinterpret_cast<const float4*>(ap + kb);
    if (kb + 4 < EE) p1 = *reinterpret_cast<const float4*>(ap + kb + 4);
    half8 av;
    av[0] = (_Float16)p0.x; av[1] = (_Float16)p0.y;
    av[2] = (_Float16)p0.z; av[3] = (_Float16)p0.w;
    av[4] = (_Float16)p1.x; av[5] = (_Float16)p1.y;
    av[6] = (_Float16)p1.z; av[7] = (_Float16)p1.w;

    const int rbase = T * 16 + 4 * (lane >> 4);
    const int cl = lane & 15;
#pragma unroll
    for (int nt = 0; nt < NT; ++nt) {
        half8 bf = *reinterpret_cast<const half8*>(&wl[nt * 64 + lane]);
        f32x4 a = {0.f, 0.f, 0.f, 0.f};
        a = __builtin_amdgcn_mfma_f32_16x16x32_f16(av, bf, a, 0, 0, 0);
        float bias = bl[nt * 16 + cl];
#pragma unroll
        for (int r = 0; r < 4; ++r) {
            if (rbase + r < Nv)
                xg[(size_t)(rbase + r) * G4 + nt * 16 + cl] = a[r] + bias;
        }
    }
}

// ---------------- Kernel 2: MFMA LSTM scan — R10 STEP, 16 waves (4/SIMD) ----------------
__device__ __forceinline__ float fast_sig(float x) { return 1.f / (1.f + __expf(-x)); }
__device__ __forceinline__ float fast_tanh(float x) { return 2.f * fast_sig(2.f * x) - 1.f; }

#define STEP(T_, CUR_, XC_, XN_)  do {                                                        \
    uint4 rb0_ = *reinterpret_cast<const uint4*>(&bfrag[CUR_][0][lane][0]);                   \
    uint4 rb1_ = *reinterpret_cast<const uint4*>(&bfrag[CUR_][1][lane][0]);                   \
    uint4 rb2_ = *reinterpret_cast<const uint4*>(&bfrag[CUR_][2][lane][0]);                   \
    uint4 rb3_ = *reinterpret_cast<const uint4*>(&bfrag[CUR_][3][lane][0]);                   \
    _Pragma("unroll")                                                                         \
    for (int it = 0; it < 2; ++it) if (it < ntile)                                            \
        XN_[it] = *reinterpret_cast<const float4*>(xgp[it] + (size_t)((T_) + 1) * G4);        \
    _Pragma("unroll")                                                                         \
    for (int it = 0; it < 2; ++it) if (it < ntile) {                                          \
        f32x4 acc = __builtin_bit_cast(f32x4, XC_[it]);                                       \
        acc = __builtin_amdgcn_mfma_f32_16x16x32_f16(af[it][0], __builtin_bit_cast(half8, rb0_), acc, 0, 0, 0); \
        acc = __builtin_amdgcn_mfma_f32_16x16x32_f16(af[it][1], __builtin_bit_cast(half8, rb1_), acc, 0, 0, 0); \
        acc = __builtin_amdgcn_mfma_f32_16x16x32_f16(af[it][2], __builtin_bit_cast(half8, rb2_), acc, 0, 0, 0); \
        acc = __builtin_amdgcn_mfma_f32_16x16x32_f16(af[it][3], __builtin_bit_cast(half8, rb3_), acc, 0, 0, 0); \
        float gi = fast_sig(acc[0]);                                                          \
        float gf = fast_sig(acc[1]);                                                          \
        float gg = fast_tanh(acc[2]);                                                         \
        float go = fast_sig(acc[3]);                                                          \
        cst[it] = gf * cst[it] + gi * gg;                                                     \
        float hv = go * fast_tanh(cst[it]);                                                   \
        int j_ = jidx[it];                                                                    \
        if ((T_) == len_n - 1) hfin[n][j_] = hv;                                              \
        int kk_ = j_ & 31;                                                                    \
        _Float16* hp_ = (_Float16*)&bfrag[(CUR_) ^ 1][j_ >> 5][((kk_ >> 3) << 4) | n][(kk_ & 7) >> 1]; \
        hp_[kk_ & 1] = (_Float16)hv;                                                          \
    }                                                                                         \
    __syncthreads();                                                                          \
} while (0)

__global__ __launch_bounds__(1024, 1) void k2_lstm(
    const float* __restrict__ xg, const int* __restrict__ lengths,
    const int* __restrict__ off, const _Float16* __restrict__ Whhf,
    const float* __restrict__ W1, const float* __restrict__ b1,
    const float* __restrict__ W2, const float* __restrict__ b2,
    const float* __restrict__ h0, const float* __restrict__ c0,
    float* __restrict__ out)
{
    __shared__ __align__(16) unsigned int bfrag[2][4][64][4];  // 8 KB fp16 B-frags
    __shared__ float hfin[16][HH];
    __shared__ float inter[16][II];
    __shared__ int len_s[16], off_s[16];

    const int tid  = threadIdx.x;
    const int lane = tid & 63;
    const int w    = tid >> 6;           // 16 waves
    const int b0   = blockIdx.x * 16;
    const int n    = lane & 15, rg = lane >> 4;

    if (tid < 16) {
        len_s[tid] = lengths[b0 + tid];
        off_s[tid] = off[b0 + tid];
    }
    for (int i = tid; i < 2 * 4 * 64 * 4; i += 1024) (&bfrag[0][0][0][0])[i] = 0u;
    __syncthreads();

    int tmax = 0;
#pragma unroll
    for (int k = 0; k < 16; ++k) tmax = max(tmax, len_s[k]);

    // 25 m-tiles over 16 waves: waves 0..8 take 2 tiles, waves 9..15 take 1
    const int ntile = (w < 9) ? 2 : 1;
    const int m0    = (w < 9) ? 2 * w : (w + 9);
    const int len_n = len_s[n];
    const size_t rowbase = (size_t)off_s[n] * G4;

    half8 af[2][4];
    float cst[2];
    int   jidx[2];
    const float* xgp[2];
    float4 xgA[2], xgB[2];
#pragma unroll
    for (int it = 0; it < 2; ++it) if (it < ntile) {
        const int m = m0 + it;
#pragma unroll
        for (int c = 0; c < 4; ++c)
            af[it][c] = reinterpret_cast<const half8*>(Whhf)[((m * 4 + c) * 64) + lane];
        const int j = 4 * m + rg;
        jidx[it] = j;
        xgp[it]  = xg + rowbase + 16 * m + 4 * rg;
        cst[it] = c0[(size_t)(b0 + n) * HH + j];
        float hv = h0[(size_t)(b0 + n) * HH + j];
        int kk = j & 31;
        _Float16* hp = (_Float16*)&bfrag[0][j >> 5][((kk >> 3) << 4) | n][(kk & 7) >> 1];
        hp[kk & 1] = (_Float16)hv;
        xgA[it] = *reinterpret_cast<const float4*>(xgp[it]);
    }
    __syncthreads();

    for (int t = 0; t < tmax; t += 2) {
        STEP(t, 0, xgA, xgB);
        if (t + 1 < tmax) STEP(t + 1, 1, xgB, xgA);
    }
    __syncthreads();

    // fused MLP over the 16 batches
    for (int o = tid; o < 16 * II; o += 1024) {
        int nn = o >> 6, i = o & 63;
        float a = b1[i];
        const float* w1r = W1 + i * HH;
        const float* hr  = &hfin[nn][0];
#pragma unroll
        for (int k = 0; k < HH; k += 4) {
            a += w1r[k] * hr[k] + w1r[k + 1] * hr[k + 1]
               + w1r[k + 2] * hr[k + 2] + w1r[k + 3] * hr[k + 3];
        }
        inter[nn][i] = fmaxf(a, 0.f);
    }
    __syncthreads();
    for (int o = tid; o < 16 * AA; o += 1024) {
        int nn = o >> 5, ai = o & 31;
        float a = b2[ai];
        const float* w2r = W2 + ai * II;
#pragma unroll
        for (int k = 0; k < II; ++k) a += w2r[k] * inter[nn][k];
        out[(size_t)(b0 + nn) * AA + ai] = a;
    }
}

extern "C" void kernel_launch(void* const* d_in, const int* in_sizes, int n_in,
                              void* d_out, int out_size, void* d_ws, size_t ws_size,
                              hipStream_t stream) {
    const float* batch  = (const float*)d_in[0];
    const int*   lengths= (const int*)  d_in[1];
    const float* W_emb  = (const float*)d_in[2];
    const float* b_emb  = (const float*)d_in[3];
    const float* W_ih   = (const float*)d_in[4];
    const float* W_hh   = (const float*)d_in[5];
    const float* b_ih   = (const float*)d_in[6];
    const float* b_hh   = (const float*)d_in[7];
    const float* W1     = (const float*)d_in[8];
    const float* b1     = (const float*)d_in[9];
    const float* W2     = (const float*)d_in[10];
    const float* b2     = (const float*)d_in[11];
    const float* h0     = (const float*)d_in[12];
    const float* c0     = (const float*)d_in[13];
    float* out = (float*)d_out;

    int*       off   = (int*)d_ws;
    float*     wsf   = (float*)d_ws;
    _Float16*  Bfrag = (_Float16*)(wsf + WS_BF_OFF);
    _Float16*  Wihf  = (_Float16*)(wsf + WS_WIHF_OFF);
    _Float16*  Whhf  = (_Float16*)(wsf + WS_WHHF_OFF);
    float*     biasc = wsf + WS_BIASC_OFF;
    float*     emb   = wsf + WS_EMB_OFF;
    float*     xg    = wsf + WS_XG_OFF;

    k0_prep<<<255, 512, 0, stream>>>(lengths, W_emb, W_ih, W_hh, b_ih, b_hh,
                                     off, Bfrag, Wihf, Whhf, biasc);
    k1_embed<<<(BB * TT + 63) / 64, 256, 0, stream>>>(batch, off, Bfrag, b_emb, emb);
    k1_xg<<<(BB * TT / 16 + 3) / 4, 256, 0, stream>>>(emb, off, Wihf, biasc, xg);
    k2_lstm<<<BB / 16, 1024, 0, stream>>>(xg, lengths, off, Whhf,
                                          W1, b1, W2, b2, h0, c0, out);
}

// Round 14
// 402.700 us; speedup vs baseline: 1.7455x; 1.1012x over previous
//
#include <hip/hip_runtime.h>

#define BB 512
#define TT 200
#define VV 2048
#define EE 20
#define HH 100
#define G4 400   // 4*H
#define II 64
#define AA 32
#define NT 25    // 16-wide tiles over gate dim 400 (rows reordered r' = 4j+g)
#define NCHUNK 64

typedef _Float16 half8 __attribute__((ext_vector_type(8)));
typedef float    f32x4 __attribute__((ext_vector_type(4)));

// ---------------- workspace layout (4-byte units) ----------------
#define WS_BF_OFF    1024                        // k1 W_emb B-frags: 65536 half
#define WS_WIHF_OFF  (WS_BF_OFF + 32768)         // W_ih' A-frags: 12800 half
#define WS_WHHF_OFF  (WS_WIHF_OFF + 6400)        // W_hh' A-frags: 51200 half
#define WS_BIASC_OFF (WS_WHHF_OFF + 25600)       // 400 f  (b_ih+b_hh, r' order)
#define WS_EMB_OFF   (WS_BIASC_OFF + 400)        // emb, COMPACTED rows: 102400x20 f

// ---------------- Kernel 0: prefix-sum + all weight fragment packs (FROZEN) ----------------
__global__ __launch_bounds__(512) void k0_prep(
    const int* __restrict__ lengths, const float* __restrict__ W_emb,
    const float* __restrict__ W_ih, const float* __restrict__ W_hh,
    const float* __restrict__ b_ih, const float* __restrict__ b_hh,
    int* __restrict__ off, _Float16* __restrict__ Bfrag,
    _Float16* __restrict__ Wihf, _Float16* __restrict__ Whhf,
    float* __restrict__ biasc)
{
    if (blockIdx.x == 0) {
        __shared__ int s[BB];
        int tid = threadIdx.x;
        s[tid] = lengths[tid];
        __syncthreads();
        for (int d = 1; d < BB; d <<= 1) {
            int v = (tid >= d) ? s[tid - d] : 0;
            __syncthreads();
            if (tid >= d) s[tid] += v;
            __syncthreads();
        }
        off[tid + 1] = s[tid];
        if (tid == 0) off[0] = 0;
        return;
    }
    int F = (blockIdx.x - 1) * 512 + threadIdx.x;
    if (F < 65536) {                       // k1 W_emb B-frags
        int e = F & 7, l = (F >> 3) & 63, nn = (F >> 9) & 1, c = F >> 10;
        int k = c * 32 + (l >> 4) * 8 + e;
        int col = nn * 16 + (l & 15);
        float v = (col < EE) ? W_emb[(size_t)col * VV + k] : 0.f;
        Bfrag[F] = (_Float16)v;
        return;
    }
    F -= 65536;
    if (F < 12800) {                       // W_ih' A-frags: [m][lane][8]
        int e = F & 7, l = (F >> 3) & 63, nt = F >> 9;
        int rp = nt * 16 + (l & 15);       // r' = 4j+g
        int j = rp >> 2, g = rp & 3;
        int k = 8 * (l >> 4) + e;          // 0..31
        float v = (k < EE) ? W_ih[(size_t)(g * HH + j) * EE + k] : 0.f;
        Wihf[F] = (_Float16)v;
        return;
    }
    F -= 12800;
    if (F < 51200) {                       // W_hh' A-frags: [m][c][lane][8]
        int e = F & 7, l = (F >> 3) & 63, c = (F >> 9) & 3, m = F >> 11;
        int rp = m * 16 + (l & 15);
        int j = rp >> 2, g = rp & 3;
        int k = 32 * c + 8 * (l >> 4) + e; // 0..127
        float v = (k < HH) ? W_hh[(size_t)(g * HH + j) * HH + k] : 0.f;
        Whhf[F] = (_Float16)v;
        return;
    }
    F -= 51200;
    if (F < 400) {                         // biasc in r' order
        int j = F >> 2, g = F & 3;
        biasc[F] = b_ih[g * HH + j] + b_hh[g * HH + j];
    }
}

// ---------------- Kernel 1: embedding GEMM via MFMA fp16 -> COMPACTED emb (FROZEN) ----------------
__global__ __launch_bounds__(256) void k1_embed(
    const float* __restrict__ batch, const int* __restrict__ off,
    const _Float16* __restrict__ Bfrag, const float* __restrict__ b_emb,
    float* __restrict__ emb)
{
    const int Nv = off[BB];
    if (blockIdx.x * 64 >= Nv) return;

    const int lane  = threadIdx.x & 63;
    const int wid   = threadIdx.x >> 6;
    const int rbase = blockIdx.x * 64 + wid * 16;

    int lrow = rbase + (lane & 15);
    int lr = (lrow < Nv) ? lrow : (Nv - 1);
    int lo = 0, hi = BB;
    while (lo + 1 < hi) {
        int mid = (lo + hi) >> 1;
        if (off[mid] <= lr) lo = mid; else hi = mid;
    }
    const int lroff = lo * TT + (lr - off[lo]);   // (b*TT + t): batch-source row

    const float* __restrict__ aptr = batch + (size_t)lroff * VV + ((lane >> 4) * 8);
    const half8* __restrict__ bptr = reinterpret_cast<const half8*>(Bfrag) + lane;

    f32x4 acc0 = {0.f, 0.f, 0.f, 0.f};
    f32x4 acc1 = {0.f, 0.f, 0.f, 0.f};

#pragma unroll 4
    for (int c = 0; c < NCHUNK; ++c) {
        float4 a0 = *reinterpret_cast<const float4*>(aptr + c * 32);
        float4 a1 = *reinterpret_cast<const float4*>(aptr + c * 32 + 4);
        half8 b0 = bptr[(c * 2 + 0) * 64];
        half8 b1 = bptr[(c * 2 + 1) * 64];
        half8 av;
        av[0] = (_Float16)a0.x; av[1] = (_Float16)a0.y;
        av[2] = (_Float16)a0.z; av[3] = (_Float16)a0.w;
        av[4] = (_Float16)a1.x; av[5] = (_Float16)a1.y;
        av[6] = (_Float16)a1.z; av[7] = (_Float16)a1.w;
        acc0 = __builtin_amdgcn_mfma_f32_16x16x32_f16(av, b0, acc0, 0, 0, 0);
        acc1 = __builtin_amdgcn_mfma_f32_16x16x32_f16(av, b1, acc1, 0, 0, 0);
    }

    const int col0 = lane & 15;
    const float bias0 = b_emb[col0];
    const float bias1 = (col0 < 4) ? b_emb[16 + col0] : 0.f;
#pragma unroll
    for (int r = 0; r < 4; ++r) {
        int srow = rbase + (lane >> 4) * 4 + r;   // compacted destination row
        if (srow < Nv) {
            emb[(size_t)srow * EE + col0] = acc0[r] + bias0;
            if (col0 < 4)
                emb[(size_t)srow * EE + 16 + col0] = acc1[r] + bias1;
        }
    }
}

// ---------------- Kernel 2: MFMA LSTM, fused x-MFMA, zero in-loop VMEM ----------------
__device__ __forceinline__ float fast_sig(float x) { return 1.f / (1.f + __expf(-x)); }
__device__ __forceinline__ float fast_tanh(float x) { return 2.f * fast_sig(2.f * x) - 1.f; }
__device__ __forceinline__ unsigned int packh2(float f0, float f1) {
    unsigned short u0 = __builtin_bit_cast(unsigned short, (_Float16)f0);
    unsigned short u1 = __builtin_bit_cast(unsigned short, (_Float16)f1);
    return ((unsigned int)u1 << 16) | u0;
}

// stage 16 steps of emb (16 batches x 20 f32 -> fp16) into estage[dst]
#define STAGE_CHUNK(DST_, CB_)  do {                                                          \
    for (int i_ = tid; i_ < 1280; i_ += 512) {                                                \
        int t16_ = i_ / 80, rem_ = i_ - t16_ * 80;                                            \
        int nn_ = rem_ / 5, q_ = rem_ - nn_ * 5;                                              \
        int ts_ = (CB_) + t16_;                                                               \
        int lm1_ = len_s[nn_] - 1;                                                            \
        ts_ = (ts_ < lm1_) ? ts_ : lm1_;                                                      \
        float4 v_ = *reinterpret_cast<const float4*>(                                         \
            emb + (size_t)(off_s[nn_] + ts_) * EE + q_ * 4);                                  \
        uint2 p_;                                                                             \
        p_.x = packh2(v_.x, v_.y);                                                            \
        p_.y = packh2(v_.z, v_.w);                                                            \
        *reinterpret_cast<uint2*>(&estage[DST_][t16_][nn_][q_ * 4]) = p_;                     \
    }                                                                                         \
} while (0)

#define STEP(T_, CUR_)  do {                                                                  \
    const int sb_ = ((T_) >> 4) & 1;                                                          \
    uint4 xb_  = *reinterpret_cast<const uint4*>(&estage[sb_][(T_) & 15][n][(lane >> 4) * 8]);\
    uint4 rb0_ = *reinterpret_cast<const uint4*>(&bfrag[CUR_][0][lane][0]);                   \
    uint4 rb1_ = *reinterpret_cast<const uint4*>(&bfrag[CUR_][1][lane][0]);                   \
    uint4 rb2_ = *reinterpret_cast<const uint4*>(&bfrag[CUR_][2][lane][0]);                   \
    uint4 rb3_ = *reinterpret_cast<const uint4*>(&bfrag[CUR_][3][lane][0]);                   \
    _Pragma("unroll")                                                                         \
    for (int it = 0; it < 4; ++it) if (it < ntile) {                                          \
        f32x4 acc = biasf[it];                                                                \
        acc = __builtin_amdgcn_mfma_f32_16x16x32_f16(wif[it], __builtin_bit_cast(half8, xb_), acc, 0, 0, 0); \
        acc = __builtin_amdgcn_mfma_f32_16x16x32_f16(af[it][0], __builtin_bit_cast(half8, rb0_), acc, 0, 0, 0); \
        acc = __builtin_amdgcn_mfma_f32_16x16x32_f16(af[it][1], __builtin_bit_cast(half8, rb1_), acc, 0, 0, 0); \
        acc = __builtin_amdgcn_mfma_f32_16x16x32_f16(af[it][2], __builtin_bit_cast(half8, rb2_), acc, 0, 0, 0); \
        acc = __builtin_amdgcn_mfma_f32_16x16x32_f16(af[it][3], __builtin_bit_cast(half8, rb3_), acc, 0, 0, 0); \
        float gi = fast_sig(acc[0]);                                                          \
        float gf = fast_sig(acc[1]);                                                          \
        float gg = fast_tanh(acc[2]);                                                         \
        float go = fast_sig(acc[3]);                                                          \
        cst[it] = gf * cst[it] + gi * gg;                                                     \
        float hv = go * fast_tanh(cst[it]);                                                   \
        int j_ = jidx[it];                                                                    \
        if ((T_) == len_n - 1) hfin[n][j_] = hv;                                              \
        int kk_ = j_ & 31;                                                                    \
        _Float16* hp_ = (_Float16*)&bfrag[(CUR_) ^ 1][j_ >> 5][((kk_ >> 3) << 4) | n][(kk_ & 7) >> 1]; \
        hp_[kk_ & 1] = (_Float16)hv;                                                          \
    }                                                                                         \
    if (((T_) & 15) == 0 && (T_) + 16 < tmax) {                                               \
        STAGE_CHUNK(sb_ ^ 1, (T_) + 16);                                                      \
    }                                                                                         \
    __syncthreads();                                                                          \
} while (0)

__global__ __launch_bounds__(512, 2) void k2_lstm(
    const float* __restrict__ emb, const int* __restrict__ lengths,
    const int* __restrict__ off, const _Float16* __restrict__ Whhf,
    const _Float16* __restrict__ Wihf, const float* __restrict__ biasc,
    const float* __restrict__ W1, const float* __restrict__ b1,
    const float* __restrict__ W2, const float* __restrict__ b2,
    const float* __restrict__ h0, const float* __restrict__ c0,
    float* __restrict__ out)
{
    __shared__ __align__(16) unsigned int bfrag[2][4][64][4];   // 8 KB h B-frags
    __shared__ __align__(16) _Float16 estage[2][16][16][40];    // 40 KB emb stage
    __shared__ float hfin[16][HH];
    __shared__ float inter[16][II];
    __shared__ int len_s[16], off_s[16];

    const int tid  = threadIdx.x;
    const int lane = tid & 63;
    const int w    = tid >> 6;
    const int b0   = blockIdx.x * 16;
    const int n    = lane & 15, rg = lane >> 4;

    if (tid < 16) {
        len_s[tid] = lengths[b0 + tid];
        off_s[tid] = off[b0 + tid];
    }
    for (int i = tid; i < 2 * 4 * 64 * 4; i += 512) (&bfrag[0][0][0][0])[i] = 0u;
    for (int i = tid; i < 2 * 16 * 16 * 40 / 2; i += 512)
        reinterpret_cast<unsigned int*>(&estage[0][0][0][0])[i] = 0u;
    __syncthreads();

    int tmax = 0;
#pragma unroll
    for (int k = 0; k < 16; ++k) tmax = max(tmax, len_s[k]);

    const int ntile = (w == 7) ? 4 : 3;
    const int m0    = (w < 7) ? 3 * w : 21;
    const int len_n = len_s[n];

    half8 af[4][4];
    half8 wif[4];
    f32x4 biasf[4];
    float cst[4];
    int   jidx[4];
#pragma unroll
    for (int it = 0; it < 4; ++it) if (it < ntile) {
        const int m = m0 + it;
#pragma unroll
        for (int c = 0; c < 4; ++c)
            af[it][c] = reinterpret_cast<const half8*>(Whhf)[((m * 4 + c) * 64) + lane];
        wif[it]   = reinterpret_cast<const half8*>(Wihf)[m * 64 + lane];
        biasf[it] = *reinterpret_cast<const f32x4*>(biasc + 16 * m + 4 * rg);
        const int j = 4 * m + rg;
        jidx[it] = j;
        cst[it] = c0[(size_t)(b0 + n) * HH + j];
        float hv = h0[(size_t)(b0 + n) * HH + j];
        int kk = j & 31;
        _Float16* hp = (_Float16*)&bfrag[0][j >> 5][((kk >> 3) << 4) | n][(kk & 7) >> 1];
        hp[kk & 1] = (_Float16)hv;
    }
    STAGE_CHUNK(0, 0);
    __syncthreads();

    for (int t = 0; t < tmax; t += 2) {
        STEP(t, 0);
        if (t + 1 < tmax) STEP(t + 1, 1);
    }
    __syncthreads();

    // fused MLP over the 16 batches
    for (int o = tid; o < 16 * II; o += 512) {
        int nn = o >> 6, i = o & 63;
        float a = b1[i];
        const float* w1r = W1 + i * HH;
        const float* hr  = &hfin[nn][0];
#pragma unroll
        for (int k = 0; k < HH; k += 4) {
            a += w1r[k] * hr[k] + w1r[k + 1] * hr[k + 1]
               + w1r[k + 2] * hr[k + 2] + w1r[k + 3] * hr[k + 3];
        }
        inter[nn][i] = fmaxf(a, 0.f);
    }
    __syncthreads();
    for (int o = tid; o < 16 * AA; o += 512) {
        int nn = o >> 5, ai = o & 31;
        float a = b2[ai];
        const float* w2r = W2 + ai * II;
#pragma unroll
        for (int k = 0; k < II; ++k) a += w2r[k] * inter[nn][k];
        out[(size_t)(b0 + nn) * AA + ai] = a;
    }
}

extern "C" void kernel_launch(void* const* d_in, const int* in_sizes, int n_in,
                              void* d_out, int out_size, void* d_ws, size_t ws_size,
                              hipStream_t stream) {
    const float* batch  = (const float*)d_in[0];
    const int*   lengths= (const int*)  d_in[1];
    const float* W_emb  = (const float*)d_in[2];
    const float* b_emb  = (const float*)d_in[3];
    const float* W_ih   = (const float*)d_in[4];
    const float* W_hh   = (const float*)d_in[5];
    const float* b_ih   = (const float*)d_in[6];
    const float* b_hh   = (const float*)d_in[7];
    const float* W1     = (const float*)d_in[8];
    const float* b1     = (const float*)d_in[9];
    const float* W2     = (const float*)d_in[10];
    const float* b2     = (const float*)d_in[11];
    const float* h0     = (const float*)d_in[12];
    const float* c0     = (const float*)d_in[13];
    float* out = (float*)d_out;

    int*       off   = (int*)d_ws;
    float*     wsf   = (float*)d_ws;
    _Float16*  Bfrag = (_Float16*)(wsf + WS_BF_OFF);
    _Float16*  Wihf  = (_Float16*)(wsf + WS_WIHF_OFF);
    _Float16*  Whhf  = (_Float16*)(wsf + WS_WHHF_OFF);
    float*     biasc = wsf + WS_BIASC_OFF;
    float*     emb   = wsf + WS_EMB_OFF;

    k0_prep<<<255, 512, 0, stream>>>(lengths, W_emb, W_ih, W_hh, b_ih, b_hh,
                                     off, Bfrag, Wihf, Whhf, biasc);
    k1_embed<<<(BB * TT + 63) / 64, 256, 0, stream>>>(batch, off, Bfrag, b_emb, emb);
    k2_lstm<<<BB / 16, 512, 0, stream>>>(emb, lengths, off, Whhf, Wihf, biasc,
                                         W1, b1, W2, b2, h0, c0, out);
}